// Round 2
// baseline (1015.314 us; speedup 1.0000x reference)
//
#include <hip/hip_runtime.h>

// SPDNet collapsed: ReEig layers are no-ops (spectrum >= 0.1 >> 1e-4 by
// Rayleigh interlacing through orthonormal-column BiMaps), so
//   X3 = (w1 w2 w3)^T X (w1 w2 w3);  out = vec(logm(X3)) @ fc
// ws layout (floats): T1[400*100] @0, W[400*50] @40000, X3[256*2500] @60000
// total 2.8 MB.

__global__ void k_mm(const float* __restrict__ A, const float* __restrict__ B,
                     float* __restrict__ C, int M, int K, int N) {
    int e = blockIdx.x * blockDim.x + threadIdx.x;
    if (e >= M * N) return;
    int r = e / N, c = e % N;
    float acc = 0.f;
    for (int k = 0; k < K; ++k) acc = fmaf(A[r * K + k], B[k * N + c], acc);
    C[e] = acc;
}

// One block per batch: X3_b = W^T X_b W.  W kept in LDS (cols padded to 64,
// zero-filled), X staged 64x64 (stride 65 -> conflict-free column reads),
// per-thread 2 rows x 8 cols register tiles; W^T*Y accumulated per row-tile.
__global__ __launch_bounds__(256) void k_bimap(const float* __restrict__ X,
                                               const float* __restrict__ W,
                                               float* __restrict__ X3) {
    __shared__ __align__(16) float Wl[400 * 64];  // 102400 B
    __shared__ __align__(16) float Xl[64 * 65];   // 16640 B
    __shared__ __align__(16) float Yb[64 * 68];   // 17408 B
    const int tid = threadIdx.x;
    const int b = blockIdx.x;
    const float* __restrict__ Xb = X + (size_t)b * 400 * 400;

    for (int e = tid; e < 400 * 64; e += 256) {
        int r = e >> 6, c = e & 63;
        Wl[e] = (c < 50) ? W[r * 50 + c] : 0.f;
    }
    // first barrier inside k-loop makes Wl visible before any use

    const int rr = tid & 31;   // rows rr and rr+32
    const int cg = tid >> 5;   // 0..7
    const int c0 = cg * 8;     // cols c0..c0+7 (of 64-padded, 50 real)

    float x30[8] = {0, 0, 0, 0, 0, 0, 0, 0};
    float x31[8] = {0, 0, 0, 0, 0, 0, 0, 0};

    for (int i0 = 0; i0 < 400; i0 += 64) {
        const int ival = (400 - i0 < 64) ? (400 - i0) : 64;
        float y0[8] = {0, 0, 0, 0, 0, 0, 0, 0};
        float y1[8] = {0, 0, 0, 0, 0, 0, 0, 0};
        for (int k0 = 0; k0 < 400; k0 += 64) {
            const int kval = (400 - k0 < 64) ? (400 - k0) : 64;
            __syncthreads();  // protect Xl from previous readers (also fences Wl once)
            for (int f = tid; f < 1024; f += 256) {
                int row = f >> 4, c4 = (f & 15) << 2;
                if ((i0 + row) < 400 && (k0 + c4) < 400) {
                    const float4 v =
                        *(const float4*)(Xb + (size_t)(i0 + row) * 400 + (k0 + c4));
                    float* d = &Xl[row * 65 + c4];
                    d[0] = v.x; d[1] = v.y; d[2] = v.z; d[3] = v.w;
                }
            }
            __syncthreads();
            #pragma unroll 4
            for (int kk = 0; kk < kval; ++kk) {
                const float a0 = Xl[rr * 65 + kk];
                const float a1 = Xl[(rr + 32) * 65 + kk];
                const float4 w0 = *(const float4*)&Wl[(k0 + kk) * 64 + c0];
                const float4 w1 = *(const float4*)&Wl[(k0 + kk) * 64 + c0 + 4];
                y0[0] = fmaf(a0, w0.x, y0[0]); y0[1] = fmaf(a0, w0.y, y0[1]);
                y0[2] = fmaf(a0, w0.z, y0[2]); y0[3] = fmaf(a0, w0.w, y0[3]);
                y0[4] = fmaf(a0, w1.x, y0[4]); y0[5] = fmaf(a0, w1.y, y0[5]);
                y0[6] = fmaf(a0, w1.z, y0[6]); y0[7] = fmaf(a0, w1.w, y0[7]);
                y1[0] = fmaf(a1, w0.x, y1[0]); y1[1] = fmaf(a1, w0.y, y1[1]);
                y1[2] = fmaf(a1, w0.z, y1[2]); y1[3] = fmaf(a1, w0.w, y1[3]);
                y1[4] = fmaf(a1, w1.x, y1[4]); y1[5] = fmaf(a1, w1.y, y1[5]);
                y1[6] = fmaf(a1, w1.z, y1[6]); y1[7] = fmaf(a1, w1.w, y1[7]);
            }
        }
        // dump Y tile (Yb disjoint from Xl; previous Yb readers finished
        // before this i-tile's k-loop barriers)
        *(float4*)&Yb[rr * 68 + c0]     = make_float4(y0[0], y0[1], y0[2], y0[3]);
        *(float4*)&Yb[rr * 68 + c0 + 4] = make_float4(y0[4], y0[5], y0[6], y0[7]);
        *(float4*)&Yb[(rr + 32) * 68 + c0]     = make_float4(y1[0], y1[1], y1[2], y1[3]);
        *(float4*)&Yb[(rr + 32) * 68 + c0 + 4] = make_float4(y1[4], y1[5], y1[6], y1[7]);
        __syncthreads();
        // X3 += W[i0:i0+ival]^T @ Ytile
        for (int kk = 0; kk < ival; ++kk) {
            const float wp0 = Wl[(i0 + kk) * 64 + rr];
            const float wp1 = Wl[(i0 + kk) * 64 + rr + 32];
            const float4 v0 = *(const float4*)&Yb[kk * 68 + c0];
            const float4 v1 = *(const float4*)&Yb[kk * 68 + c0 + 4];
            x30[0] = fmaf(wp0, v0.x, x30[0]); x30[1] = fmaf(wp0, v0.y, x30[1]);
            x30[2] = fmaf(wp0, v0.z, x30[2]); x30[3] = fmaf(wp0, v0.w, x30[3]);
            x30[4] = fmaf(wp0, v1.x, x30[4]); x30[5] = fmaf(wp0, v1.y, x30[5]);
            x30[6] = fmaf(wp0, v1.z, x30[6]); x30[7] = fmaf(wp0, v1.w, x30[7]);
            x31[0] = fmaf(wp1, v0.x, x31[0]); x31[1] = fmaf(wp1, v0.y, x31[1]);
            x31[2] = fmaf(wp1, v0.z, x31[2]); x31[3] = fmaf(wp1, v0.w, x31[3]);
            x31[4] = fmaf(wp1, v1.x, x31[4]); x31[5] = fmaf(wp1, v1.y, x31[5]);
            x31[6] = fmaf(wp1, v1.z, x31[6]); x31[7] = fmaf(wp1, v1.w, x31[7]);
        }
    }
    float* __restrict__ dst = X3 + (size_t)b * 2500;
    #pragma unroll
    for (int q = 0; q < 8; ++q) {
        int c = c0 + q;
        if (c < 50) {
            dst[rr * 50 + c] = x30[q];
            if (rr + 32 < 50) dst[(rr + 32) * 50 + c] = x31[q];
        }
    }
}

// round-robin tournament pairing: round r (0..48), pair m (0..24) over 50 idx
__device__ __forceinline__ void pair_pq(int m, int r, int& p, int& q) {
    if (m == 0) { p = 49; q = r; }
    else {
        p = r + m;        if (p >= 49) p -= 49;
        q = r + 49 - m;   if (q >= 49) q -= 49;
    }
}

// One block per batch: parallel Jacobi eigendecomposition of 50x50 SPD,
// then L = V diag(log d) V^T and logits = vec(L) @ fc.
__global__ __launch_bounds__(256) void k_eiglog(const float* __restrict__ X3,
                                                const float* __restrict__ fc,
                                                float* __restrict__ out) {
    __shared__ __align__(16) float A[50 * 54];
    __shared__ __align__(16) float VT[50 * 54];  // rows of VT = eigvec columns of V
    __shared__ __align__(16) float L[50 * 54];
    __shared__ float pc[25], ps[25];
    __shared__ float logd[50];
    __shared__ float red[256 * 7];
    const int tid = threadIdx.x;
    const int b = blockIdx.x;
    const float* __restrict__ src = X3 + (size_t)b * 2500;

    for (int e = tid; e < 2500; e += 256) A[(e / 50) * 54 + (e % 50)] = src[e];
    for (int e = tid; e < 2700; e += 256) VT[e] = 0.f;
    __syncthreads();
    if (tid < 50) VT[tid * 54 + tid] = 1.f;
    __syncthreads();

    for (int sweep = 0; sweep < 8; ++sweep) {
        for (int r = 0; r < 49; ++r) {
            if (tid < 25) {
                int p, q; pair_pq(tid, r, p, q);
                float app = A[p * 54 + p], aqq = A[q * 54 + q], apq = A[p * 54 + q];
                float c = 1.f, s = 0.f;
                if (fabsf(apq) > 1e-20f) {
                    float tau = (aqq - app) / (2.f * apq);
                    float t = 1.f / (fabsf(tau) + sqrtf(1.f + tau * tau));
                    t = (tau >= 0.f) ? t : -t;
                    c = rsqrtf(1.f + t * t);
                    s = t * c;
                }
                pc[tid] = c; ps[tid] = s;
            }
            __syncthreads();
            // row rotations on A and VT (float2 over columns): disjoint rows
            for (int e = tid; e < 1250; e += 256) {
                int idx = e;
                float2* M2 = (float2*)A;
                if (idx >= 625) { idx -= 625; M2 = (float2*)VT; }
                int m = idx / 25, ch = idx % 25;
                int p, q; pair_pq(m, r, p, q);
                float c = pc[m], s = ps[m];
                float2 u = M2[p * 27 + ch], v = M2[q * 27 + ch];
                float2 nu, nv;
                nu.x = fmaf(c, u.x, -s * v.x);
                nu.y = fmaf(c, u.y, -s * v.y);
                nv.x = fmaf(s, u.x, c * v.x);
                nv.y = fmaf(s, u.y, c * v.y);
                M2[p * 27 + ch] = nu;
                M2[q * 27 + ch] = nv;
            }
            __syncthreads();
            // column rotations on A: disjoint column pairs
            for (int e = tid; e < 1250; e += 256) {
                int m = e / 50, i = e % 50;
                int p, q; pair_pq(m, r, p, q);
                float c = pc[m], s = ps[m];
                float x = A[i * 54 + p], y = A[i * 54 + q];
                A[i * 54 + p] = fmaf(c, x, -s * y);
                A[i * 54 + q] = fmaf(s, x, c * y);
            }
            __syncthreads();
        }
    }

    if (tid < 50) logd[tid] = logf(fmaxf(A[tid * 54 + tid], 1e-10f));
    __syncthreads();

    // L[i][j] = sum_k VT[k][i] * logd[k] * VT[k][j]
    for (int e = tid; e < 2500; e += 256) {
        int i = e / 50, j = e % 50;
        float acc = 0.f;
        for (int k = 0; k < 50; ++k)
            acc = fmaf(VT[k * 54 + i] * logd[k], VT[k * 54 + j], acc);
        L[i * 54 + j] = acc;
    }
    __syncthreads();

    float part[7] = {0, 0, 0, 0, 0, 0, 0};
    for (int e = tid; e < 2500; e += 256) {
        float lv = L[(e / 50) * 54 + (e % 50)];
        #pragma unroll
        for (int n = 0; n < 7; ++n) part[n] = fmaf(lv, fc[e * 7 + n], part[n]);
    }
    #pragma unroll
    for (int n = 0; n < 7; ++n) red[tid * 7 + n] = part[n];
    __syncthreads();
    for (int s = 128; s > 0; s >>= 1) {
        if (tid < s) {
            #pragma unroll
            for (int n = 0; n < 7; ++n) red[tid * 7 + n] += red[(tid + s) * 7 + n];
        }
        __syncthreads();
    }
    if (tid < 7) out[b * 7 + tid] = red[tid];
}

extern "C" void kernel_launch(void* const* d_in, const int* in_sizes, int n_in,
                              void* d_out, int out_size, void* d_ws, size_t ws_size,
                              hipStream_t stream) {
    const float* X  = (const float*)d_in[0];
    const float* w1 = (const float*)d_in[1];
    const float* w2 = (const float*)d_in[2];
    const float* w3 = (const float*)d_in[3];
    const float* fc = (const float*)d_in[4];
    float* out = (float*)d_out;

    float* ws = (float*)d_ws;
    float* T1 = ws;            // 400*100
    float* W  = ws + 40000;    // 400*50
    float* X3 = ws + 60000;    // 256*2500

    k_mm<<<(400 * 100 + 255) / 256, 256, 0, stream>>>(w1, w2, T1, 400, 200, 100);
    k_mm<<<(400 * 50 + 255) / 256, 256, 0, stream>>>(T1, w3, W, 400, 100, 50);
    k_bimap<<<256, 256, 0, stream>>>(X, W, X3);
    k_eiglog<<<256, 256, 0, stream>>>(X3, fc, out);
}